// Round 3
// baseline (181.117 us; speedup 1.0000x reference)
//
#include <hip/hip_runtime.h>

// FFF tree traversal, round 3: level-split multi-pass so each pass's weight
// working set fits one XCD's 4 MiB L2.
//   prep : w2 fp32 -> bf16 (4.19 MB, L2-resident in pass 3)
//   pass1: levels 0-9 traversal  (w1[0..1022] = 4.09 MB L2-resident);
//          x loaded nontemporal (no-allocate) so it can't evict weights.
//          Emits scores[0..9] + node10 per row (48 B/row).
//   pass2: level-10 dot only     (w1[1023..2046] = 4.19 MB L2-resident).
//   pass3: y = sum_l s_l * w2[n_l] — no serial chain, streaming; path
//          reconstructed from node10 via parent = (n-1)>>1.
// y stores are PLAIN (round-2 nt-stores doubled WRITE_SIZE: 131->287 MB).

typedef float          f32x4 __attribute__((ext_vector_type(4)));
typedef unsigned short u16x4 __attribute__((ext_vector_type(4)));

#define FFF_BATCH  32768
#define FFF_NIN    1024
#define FFF_NOUT   1024
#define FFF_NODES  2047
#define SSTRIDE    12   // floats per row of state: scores[0..10], node10 bits

__device__ __forceinline__ f32x4 ld_nt4f(const f32x4* p) { return __builtin_nontemporal_load(p); }

// ---- prep: w2 fp32 -> bf16 (RNE) ----
__global__ void fff_w2_to_bf16(const float* __restrict__ w2, unsigned short* __restrict__ o)
{
    const int i = blockIdx.x * blockDim.x + threadIdx.x;   // one float4 / thread
    const f32x4 v = reinterpret_cast<const f32x4*>(w2)[i];
    u16x4 u;
#pragma unroll
    for (int k = 0; k < 4; ++k) {
        unsigned b = __float_as_uint(v[k]);
        b = (b + 0x7FFFu + ((b >> 16) & 1u)) >> 16;        // round-to-nearest-even
        u[k] = (unsigned short)b;
    }
    reinterpret_cast<u16x4*>(o)[i] = u;
}

// ---- pass 1: levels 0..9 ----
__global__ __launch_bounds__(256) void fff_pass1(
    const float* __restrict__ x, const float* __restrict__ w1s,
    float* __restrict__ state)
{
    const int wave = threadIdx.x >> 6;
    const int lane = threadIdx.x & 63;
    const int row0 = (blockIdx.x * 4 + wave) * 2;

    f32x4 xv[2][4];
#pragma unroll
    for (int r = 0; r < 2; ++r) {
        const f32x4* x4 = reinterpret_cast<const f32x4*>(x + (size_t)(row0 + r) * FFF_NIN);
#pragma unroll
        for (int c = 0; c < 4; ++c) xv[r][c] = ld_nt4f(&x4[c * 64 + lane]);
    }

    int node[2] = {0, 0};
    float sc[2][10];

#pragma unroll
    for (int l = 0; l < 10; ++l) {
        f32x4 wv[2][4];
#pragma unroll
        for (int r = 0; r < 2; ++r) {
            const f32x4* w14 = reinterpret_cast<const f32x4*>(w1s + (size_t)node[r] * FFF_NIN);
#pragma unroll
            for (int c = 0; c < 4; ++c) wv[r][c] = w14[c * 64 + lane];
        }
        float p[2];
#pragma unroll
        for (int r = 0; r < 2; ++r) {
            float s = 0.f;
#pragma unroll
            for (int c = 0; c < 4; ++c) {
                s = fmaf(xv[r][c][0], wv[r][c][0], s);
                s = fmaf(xv[r][c][1], wv[r][c][1], s);
                s = fmaf(xv[r][c][2], wv[r][c][2], s);
                s = fmaf(xv[r][c][3], wv[r][c][3], s);
            }
            p[r] = s;
        }
#pragma unroll
        for (int m = 1; m < 64; m <<= 1) {
            const float t0 = __shfl_xor(p[0], m, 64);
            const float t1 = __shfl_xor(p[1], m, 64);
            p[0] += t0; p[1] += t1;
        }
        sc[0][l] = p[0]; sc[1][l] = p[1];
        node[0] = node[0] * 2 + 1 + ((p[0] > 0.f) ? 1 : 0);
        node[1] = node[1] * 2 + 1 + ((p[1] > 0.f) ? 1 : 0);
    }

#pragma unroll
    for (int r = 0; r < 2; ++r) {
        float v = sc[r][0];
        v = (lane == 1) ? sc[r][1] : v;  v = (lane == 2) ? sc[r][2] : v;
        v = (lane == 3) ? sc[r][3] : v;  v = (lane == 4) ? sc[r][4] : v;
        v = (lane == 5) ? sc[r][5] : v;  v = (lane == 6) ? sc[r][6] : v;
        v = (lane == 7) ? sc[r][7] : v;  v = (lane == 8) ? sc[r][8] : v;
        v = (lane == 9) ? sc[r][9] : v;
        const size_t base = (size_t)(row0 + r) * SSTRIDE;
        if (lane < 10)  state[base + lane] = v;
        if (lane == 11) state[base + 11]   = __int_as_float(node[r]);
    }
}

// ---- pass 2: level 10 dot only ----
__global__ __launch_bounds__(256) void fff_pass2(
    const float* __restrict__ x, const float* __restrict__ w1s,
    float* __restrict__ state)
{
    const int wave = threadIdx.x >> 6;
    const int lane = threadIdx.x & 63;
    const int row0 = (blockIdx.x * 4 + wave) * 2;

    int node[2];
#pragma unroll
    for (int r = 0; r < 2; ++r)
        node[r] = __float_as_int(state[(size_t)(row0 + r) * SSTRIDE + 11]);

    float p[2] = {0.f, 0.f};
#pragma unroll
    for (int r = 0; r < 2; ++r) {
        const f32x4* x4  = reinterpret_cast<const f32x4*>(x + (size_t)(row0 + r) * FFF_NIN);
        const f32x4* w14 = reinterpret_cast<const f32x4*>(w1s + (size_t)node[r] * FFF_NIN);
        float s = 0.f;
#pragma unroll
        for (int c = 0; c < 4; ++c) {
            const f32x4 xc = ld_nt4f(&x4[c * 64 + lane]);
            const f32x4 wc = w14[c * 64 + lane];
            s = fmaf(xc[0], wc[0], s);
            s = fmaf(xc[1], wc[1], s);
            s = fmaf(xc[2], wc[2], s);
            s = fmaf(xc[3], wc[3], s);
        }
        p[r] = s;
    }
#pragma unroll
    for (int m = 1; m < 64; m <<= 1) {
        const float t0 = __shfl_xor(p[0], m, 64);
        const float t1 = __shfl_xor(p[1], m, 64);
        p[0] += t0; p[1] += t1;
    }
    if (lane == 10) {
        state[(size_t)(row0 + 0) * SSTRIDE + 10] = p[0];
        state[(size_t)(row0 + 1) * SSTRIDE + 10] = p[1];
    }
}

// ---- pass 3: y = sum_l s_l * w2b[n_l] ----
__global__ __launch_bounds__(256) void fff_pass3(
    const float* __restrict__ state, const unsigned short* __restrict__ w2b,
    float* __restrict__ y)
{
    const int wave = threadIdx.x >> 6;
    const int lane = threadIdx.x & 63;
    const int row0 = (blockIdx.x * 4 + wave) * 2;

    float v[2];
#pragma unroll
    for (int r = 0; r < 2; ++r)
        v[r] = (lane < SSTRIDE) ? state[(size_t)(row0 + r) * SSTRIDE + lane] : 0.f;

    float s[2][11];
    int   n[2][11];
#pragma unroll
    for (int r = 0; r < 2; ++r) {
#pragma unroll
        for (int l = 0; l < 11; ++l) s[r][l] = __shfl(v[r], l, 64);
        n[r][10] = __float_as_int(__shfl(v[r], 11, 64));
#pragma unroll
        for (int l = 9; l >= 0; --l) n[r][l] = (n[r][l + 1] - 1) >> 1;
    }

    f32x4 acc[2][4];
#pragma unroll
    for (int r = 0; r < 2; ++r)
#pragma unroll
        for (int c = 0; c < 4; ++c) acc[r][c] = (f32x4)(0.f);

#pragma unroll
    for (int l = 0; l < 11; ++l) {
#pragma unroll
        for (int r = 0; r < 2; ++r) {
            const u16x4* w24 = reinterpret_cast<const u16x4*>(w2b + (size_t)n[r][l] * FFF_NOUT);
            const float sc = s[r][l];
#pragma unroll
            for (int c = 0; c < 4; ++c) {
                const u16x4 u = w24[c * 64 + lane];
                acc[r][c][0] = fmaf(sc, __uint_as_float((unsigned)u[0] << 16), acc[r][c][0]);
                acc[r][c][1] = fmaf(sc, __uint_as_float((unsigned)u[1] << 16), acc[r][c][1]);
                acc[r][c][2] = fmaf(sc, __uint_as_float((unsigned)u[2] << 16), acc[r][c][2]);
                acc[r][c][3] = fmaf(sc, __uint_as_float((unsigned)u[3] << 16), acc[r][c][3]);
            }
        }
    }

#pragma unroll
    for (int r = 0; r < 2; ++r) {
        f32x4* y4 = reinterpret_cast<f32x4*>(y + (size_t)(row0 + r) * FFF_NOUT);
#pragma unroll
        for (int c = 0; c < 4; ++c) y4[c * 64 + lane] = acc[r][c];
    }
}

// ---- fallback (proven round-1 fused kernel) if ws too small ----
__global__ __launch_bounds__(256, 4) void fff_fused(
    const float* __restrict__ x, const float* __restrict__ w1s,
    const float* __restrict__ w2s, float* __restrict__ y)
{
    const int row  = blockIdx.x * 4 + (threadIdx.x >> 6);
    const int lane = threadIdx.x & 63;
    const f32x4* x4 = reinterpret_cast<const f32x4*>(x + (size_t)row * FFF_NIN);
    f32x4 xv[4];
#pragma unroll
    for (int c = 0; c < 4; ++c) xv[c] = x4[c * 64 + lane];
    f32x4 acc[4];
#pragma unroll
    for (int c = 0; c < 4; ++c) acc[c] = (f32x4)(0.f);
    int node = 0;
#pragma unroll
    for (int l = 0; l < 11; ++l) {
        const f32x4* w14 = reinterpret_cast<const f32x4*>(w1s + (size_t)node * FFF_NIN);
        const f32x4* w24 = reinterpret_cast<const f32x4*>(w2s + (size_t)node * FFF_NOUT);
        f32x4 wv[4], uv[4];
#pragma unroll
        for (int c = 0; c < 4; ++c) { wv[c] = w14[c * 64 + lane]; uv[c] = w24[c * 64 + lane]; }
        float p = 0.f;
#pragma unroll
        for (int c = 0; c < 4; ++c) {
            p = fmaf(xv[c][0], wv[c][0], p); p = fmaf(xv[c][1], wv[c][1], p);
            p = fmaf(xv[c][2], wv[c][2], p); p = fmaf(xv[c][3], wv[c][3], p);
        }
#pragma unroll
        for (int m = 1; m < 64; m <<= 1) p += __shfl_xor(p, m, 64);
#pragma unroll
        for (int c = 0; c < 4; ++c) {
            acc[c][0] = fmaf(p, uv[c][0], acc[c][0]); acc[c][1] = fmaf(p, uv[c][1], acc[c][1]);
            acc[c][2] = fmaf(p, uv[c][2], acc[c][2]); acc[c][3] = fmaf(p, uv[c][3], acc[c][3]);
        }
        node = node * 2 + 1 + ((p > 0.f) ? 1 : 0);
    }
    f32x4* y4 = reinterpret_cast<f32x4*>(y + (size_t)row * FFF_NOUT);
#pragma unroll
    for (int c = 0; c < 4; ++c) y4[c * 64 + lane] = acc[c];
}

extern "C" void kernel_launch(void* const* d_in, const int* in_sizes, int n_in,
                              void* d_out, int out_size, void* d_ws, size_t ws_size,
                              hipStream_t stream) {
    const float* x   = (const float*)d_in[0];
    const float* w1s = (const float*)d_in[1];
    const float* w2s = (const float*)d_in[2];
    float* y = (float*)d_out;

    const size_t w2b_bytes   = (size_t)FFF_NODES * FFF_NOUT * sizeof(unsigned short); // 4,192,256
    const size_t state_bytes = (size_t)FFF_BATCH * SSTRIDE * sizeof(float);           // 1,572,864
    const size_t need = w2b_bytes + state_bytes;

    if (ws_size >= need) {
        unsigned short* w2b  = (unsigned short*)d_ws;
        float* state = (float*)((char*)d_ws + w2b_bytes);
        const int blocks = FFF_BATCH / 8;  // 4 waves/block * 2 rows/wave
        fff_w2_to_bf16<<<FFF_NODES, 256, 0, stream>>>(w2s, w2b);
        fff_pass1<<<blocks, 256, 0, stream>>>(x, w1s, state);
        fff_pass2<<<blocks, 256, 0, stream>>>(x, w1s, state);
        fff_pass3<<<blocks, 256, 0, stream>>>(state, w2b, y);
    } else {
        fff_fused<<<FFF_BATCH / 4, 256, 0, stream>>>(x, w1s, w2s, y);
    }
}